// Round 22
// baseline (115.862 us; speedup 1.0000x reference)
//
#include <hip/hip_runtime.h>
#include <math.h>

#define T_DIM 2048
#define B_DIM 8
#define D_DIM 1024
#define N_DIM 64
#define NCHUNK 16
#define CHUNK_LEN 128              // T_DIM / NCHUNK
#define DECAY 0.9f
#define EPS 1e-8f
#define RADIUS 0.5f

typedef __attribute__((ext_vector_type(8))) short short8;   // bf16x8 MFMA frag
typedef __attribute__((ext_vector_type(4))) float f32x4;

static __device__ __forceinline__ unsigned short f2bf(float f) {
    unsigned u = __float_as_uint(f);
    u += 0x7FFFu + ((u >> 16) & 1u);          // RNE
    return (unsigned short)(u >> 16);
}
static __device__ __forceinline__ float bf2f(unsigned short h) {
    return __uint_as_float(((unsigned)h) << 16);
}

// counted barrier: flush LDS writes, sync waves, do NOT drain vmcnt (T4)
static __device__ __forceinline__ void bar_lgkm() {
    asm volatile("s_waitcnt lgkmcnt(0)" ::: "memory");
    __builtin_amdgcn_s_barrier();
    asm volatile("" ::: "memory");
}

// ------- gram + UNSCALED pack: 192 blocks = (mat, row i) -------
// mat<2: G[mat] row i (as before). ALL blocks: pack row i (held in wsr LDS)
// into the fragment-major hi/lo layout (R6-proven formula), unscaled —
// the spectral scale is applied in scan (scalar factor on k). Kills build_wt.
__global__ __launch_bounds__(256)
void gram_pack_kernel(const float* __restrict__ Wk, const float* __restrict__ Wv,
                      const float* __restrict__ Wq, float* __restrict__ G,
                      unsigned short* __restrict__ BPh, unsigned short* __restrict__ BPl) {
    int mat = blockIdx.x >> 6;     // 0=k,1=v,2=q
    int i   = blockIdx.x & 63;
    const float* W = (mat == 0) ? Wk : (mat == 1) ? Wv : Wq;
    __shared__ float wsr[D_DIM];
    __shared__ float part[4][64];
    int tid = threadIdx.x;
    *(float4*)&wsr[tid * 4] = *(const float4*)(W + (size_t)i * D_DIM + tid * 4);
    __syncthreads();
    if (mat < 2) {
        int j = tid & 63, p = tid >> 6;
        const float* wj = W + (size_t)j * D_DIM + p * 256;
        const float* wp = wsr + p * 256;
        float acc = 0.f;
        #pragma unroll 16
        for (int k = 0; k < 256; k += 4) {
            float4 a = *(const float4*)(wj + k);
            float4 b = *(const float4*)(wp + k);
            acc += a.x * b.x + a.y * b.y + a.z * b.z + a.w * b.w;
        }
        part[p][j] = acc;
        __syncthreads();
        if (tid < 64)
            G[((size_t)mat * 64 + i) * 64 + tid] =
                part[0][tid] + part[1][tid] + part[2][tid] + part[3][tid];
    }
    // pack: element (c=i, k) -> idx = g*16384 + s*1024 + kk*512 + (flh*16+fl)*8 + e
    int g  = mat * 4 + (i >> 4);
    int fl = i & 15;
    float4 w4 = *(const float4*)&wsr[tid * 4];
    float vals[4] = {w4.x, w4.y, w4.z, w4.w};
    #pragma unroll
    for (int e4 = 0; e4 < 4; ++e4) {
        int k = tid * 4 + e4;
        unsigned short h = f2bf(vals[e4]);
        unsigned short l = f2bf(vals[e4] - bf2f(h));
        int s   = k >> 6;
        int kk  = (k >> 5) & 1;
        int flh = (k >> 3) & 3;
        int e   = k & 7;
        size_t idx = (size_t)g * 16384 + s * 1024 + kk * 512 + (flh * 16 + fl) * 8 + e;
        BPh[idx] = h;
        BPl[idx] = l;
    }
}

// ------------- projections (R13 structure, byte-identical; pack now unscaled) -------------
#define PBM 32
#define KSTAGE 128
__global__ __launch_bounds__(256)
void proj_mfma_kernel(const float* __restrict__ x,
                      const unsigned short* __restrict__ BPh,
                      const unsigned short* __restrict__ BPl,
                      float* __restrict__ kvq) {
    __shared__ __align__(16) unsigned short ldsA[2][PBM * KSTAGE];  // 16 KB
    int tid = threadIdx.x;
    int lane = tid & 63;
    int wv = tid >> 6;                 // 0..3 -> cols [wv*48, +48)
    int fl15 = lane & 15;
    int flh = lane >> 4;               // 0..3
    int rowBase = blockIdx.x * PBM;

    int r_st = tid >> 3;
    int sub  = tid & 7;
    const float* xrow = x + (size_t)(rowBase + r_st) * D_DIM + sub * 8;
    int wb0 = r_st * 256 + ((sub * 16) ^ ((r_st & 7) << 4));
    int wb1 = wb0 + 128;

    const unsigned short* bbh = BPh + (size_t)(wv * 3) * 16384 + lane * 8;
    const unsigned short* bbl = BPl + (size_t)(wv * 3) * 16384 + lane * 8;

    f32x4 acc[2][3];
    #pragma unroll
    for (int mt = 0; mt < 2; ++mt)
        #pragma unroll
        for (int nt = 0; nt < 3; ++nt) acc[mt][nt] = (f32x4)(0.f);

    // prologue: stage 0 -> buf0 (single bf16 plane); stage 1 -> regs p*
    {
        float4 c0 = *(const float4*)(xrow);
        float4 c1 = *(const float4*)(xrow + 4);
        float4 c2 = *(const float4*)(xrow + 64);
        float4 c3 = *(const float4*)(xrow + 68);
        float v0[8] = {c0.x, c0.y, c0.z, c0.w, c1.x, c1.y, c1.z, c1.w};
        float v1[8] = {c2.x, c2.y, c2.z, c2.w, c3.x, c3.y, c3.z, c3.w};
        short8 h0, h1;
        #pragma unroll
        for (int e = 0; e < 8; ++e) {
            h0[e] = (short)f2bf(v0[e]);
            h1[e] = (short)f2bf(v1[e]);
        }
        char* pH = (char*)&ldsA[0][0];
        *(short8*)(pH + wb0) = h0;
        *(short8*)(pH + wb1) = h1;
    }
    float4 p0 = *(const float4*)(xrow + KSTAGE);
    float4 p1 = *(const float4*)(xrow + KSTAGE + 4);
    float4 p2 = *(const float4*)(xrow + KSTAGE + 64);
    float4 p3 = *(const float4*)(xrow + KSTAGE + 68);
    bar_lgkm();

    #pragma unroll 1
    for (int qt = 0; qt < 8; ++qt) {
        int buf = qt & 1;
        const char* pH = (const char*)&ldsA[buf][0];
        #pragma unroll
        for (int s = 0; s < 2; ++s) {
            int sg = qt * 2 + s;
            short8 bh[2][3], bl[2][3];
            #pragma unroll
            for (int nt = 0; nt < 3; ++nt)
                #pragma unroll
                for (int kk = 0; kk < 2; ++kk) {
                    size_t off = (size_t)nt * 16384 + sg * 1024 + kk * 512;
                    bh[kk][nt] = *(const short8*)(bbh + off);
                    bl[kk][nt] = *(const short8*)(bbl + off);
                }
            #pragma unroll
            for (int kk = 0; kk < 2; ++kk) {
                short8 ah[2];
                #pragma unroll
                for (int mt = 0; mt < 2; ++mt) {
                    int row = mt * 16 + fl15;
                    int off = row * 256 + s * 128 +
                              ((kk * 64 + flh * 16) ^ ((row & 7) << 4));
                    ah[mt] = *(const short8*)(pH + off);
                }
                #pragma unroll
                for (int mt = 0; mt < 2; ++mt)
                    #pragma unroll
                    for (int nt = 0; nt < 3; ++nt) {
                        acc[mt][nt] = __builtin_amdgcn_mfma_f32_16x16x32_bf16(
                            ah[mt], bh[kk][nt], acc[mt][nt], 0, 0, 0);
                        acc[mt][nt] = __builtin_amdgcn_mfma_f32_16x16x32_bf16(
                            ah[mt], bl[kk][nt], acc[mt][nt], 0, 0, 0);
                    }
            }
        }
        // x prefetch for stage qt+2, issued after all B loads of this iter
        float4 q0, q1, q2, q3;
        if (qt < 6) {
            const float* nx = xrow + (qt + 2) * KSTAGE;
            q0 = *(const float4*)(nx);
            q1 = *(const float4*)(nx + 4);
            q2 = *(const float4*)(nx + 64);
            q3 = *(const float4*)(nx + 68);
        }
        // write stage qt+1 (regs p*) into the other buffer
        if (qt < 7) {
            float v0[8] = {p0.x, p0.y, p0.z, p0.w, p1.x, p1.y, p1.z, p1.w};
            float v1[8] = {p2.x, p2.y, p2.z, p2.w, p3.x, p3.y, p3.z, p3.w};
            short8 h0, h1;
            #pragma unroll
            for (int e = 0; e < 8; ++e) {
                h0[e] = (short)f2bf(v0[e]);
                h1[e] = (short)f2bf(v1[e]);
            }
            char* qH = (char*)&ldsA[buf ^ 1][0];
            *(short8*)(qH + wb0) = h0;
            *(short8*)(qH + wb1) = h1;
        }
        bar_lgkm();
        p0 = q0; p1 = q1; p2 = q2; p3 = q3;
    }

    // epilogue: C/D layout col=lane&15, row=(lane>>4)*4+reg  [m89]
    #pragma unroll
    for (int mt = 0; mt < 2; ++mt)
        #pragma unroll
        for (int nt = 0; nt < 3; ++nt) {
            int col = wv * 48 + nt * 16 + fl15;
            #pragma unroll
            for (int r = 0; r < 4; ++r) {
                int row = rowBase + mt * 16 + flh * 4 + r;
                kvq[(size_t)row * 192 + col] = acc[mt][nt][r];
            }
        }
}

// ------------- scan: power-iteration head (scales) + warm-up + NT store scan -------------
// Head: wave-redundant 3-iter power on G[k],G[v] (same ops as the proven build
// version; per-wave usw rows) -> sckv = sck*scv. k4 is pre-scaled by sckv each
// step (s accumulates (sck*k)·(scv*v)); q/out/S0 paths unchanged.
#define SC_TILE 8
__global__ __launch_bounds__(256)
void scan_kernel(const float* __restrict__ kvq,
                 const float* __restrict__ S0,
                 const float* __restrict__ G,
                 const float* __restrict__ uk, const float* __restrict__ uv,
                 float* __restrict__ out,      // [T,B,n]
                 float* __restrict__ S_all) {  // [T+1,B,n,n]
    __shared__ __align__(16) float P[4][SC_TILE][4][20];
    __shared__ float Gs[64][65];
    __shared__ float usw[4][64];
    int tid  = threadIdx.x;
    int widL = tid >> 6;
    int lane = tid & 63;

    // ---- power head ----
    float scs[2];
    #pragma unroll
    for (int m2 = 0; m2 < 2; ++m2) {
        __syncthreads();                       // Gs reuse safety (all waves done)
        #pragma unroll
        for (int e = 0; e < 16; ++e) {
            int idx = e * 256 + tid;
            Gs[idx >> 6][idx & 63] = G[(size_t)m2 * 4096 + idx];
        }
        usw[widL][lane] = (m2 ? uv : uk)[lane];
        __syncthreads();
        float sigma = 0.f;
        for (int it = 0; it < 3; ++it) {
            float t = 0.f;
            #pragma unroll
            for (int jj = 0; jj < 64; ++jj)
                t += Gs[lane][jj] * usw[widL][jj];
            float nv2 = usw[widL][lane] * t;
            #pragma unroll
            for (int o = 32; o > 0; o >>= 1) nv2 += __shfl_xor(nv2, o, 64);
            float nv = sqrtf(fmaxf(nv2, 0.f));
            float ur = t / (nv + EPS);
            float nu2 = ur * ur;
            #pragma unroll
            for (int o = 32; o > 0; o >>= 1) nu2 += __shfl_xor(nu2, o, 64);
            float nu = sqrtf(nu2);
            if (it == 2) sigma = nu2 / (nu + EPS);
            usw[widL][lane] = ur / (nu + EPS);   // wave-local LDS row
        }
        scs[m2] = RADIUS / (sigma + EPS);
    }
    float sckv = scs[0] * scs[1];
    __syncthreads();

    int r  = lane >> 4;          // row within wave's 4
    int jq = lane & 15;          // col quad
    int blk = blockIdx.x;
    int c  = blk >> 5;           // 0..15
    int b  = (blk >> 2) & 7;
    int ig = blk & 3;
    int i0 = ig * 16 + widL * 4;
    int i  = i0 + r;

    int pp   = lane >> 1;
    int ur2  = pp >> 2;
    int rr   = pp & 3;
    int half = lane & 1;

    if (c == 0) {
        f32x4 s0v = *(const f32x4*)&S0[((size_t)b * 64 + i) * 64 + jq * 4];
        *(f32x4*)&S_all[(size_t)b * 4096 + (size_t)i * 64 + jq * 4] = s0v;
    }

    f32x4 s = (f32x4)(0.f);
    if (c > 0) {
        int tp = (c - 1) * CHUNK_LEN;
        #pragma unroll 4
        for (int u = 0; u < CHUNK_LEN; ++u) {
            const float* base = kvq + (size_t)((tp + u) * B_DIM + b) * 192;
            f32x4 k4 = *(const f32x4*)(base + jq * 4);
            float v  = base[64 + i] * sckv;
            s.x = __builtin_fmaf(DECAY, s.x, v * k4.x);
            s.y = __builtin_fmaf(DECAY, s.y, v * k4.y);
            s.z = __builtin_fmaf(DECAY, s.z, v * k4.z);
            s.w = __builtin_fmaf(DECAY, s.w, v * k4.w);
        }
    }

    int t0 = c * CHUNK_LEN;
    for (int tb = 0; tb < CHUNK_LEN; tb += SC_TILE) {
        #pragma unroll
        for (int u = 0; u < SC_TILE; ++u) {
            int t = t0 + tb + u;
            const float* base = kvq + (size_t)(t * B_DIM + b) * 192;
            f32x4 k4 = *(const f32x4*)(base + jq * 4);
            f32x4 q4 = *(const f32x4*)(base + 128 + jq * 4);
            float v  = base[64 + i] * sckv;
            s.x = __builtin_fmaf(DECAY, s.x, v * k4.x);
            s.y = __builtin_fmaf(DECAY, s.y, v * k4.y);
            s.z = __builtin_fmaf(DECAY, s.z, v * k4.z);
            s.w = __builtin_fmaf(DECAY, s.w, v * k4.w);
            __builtin_nontemporal_store(
                s, (f32x4*)&S_all[((size_t)(t + 1) * B_DIM + b) * 4096 +
                                  (size_t)i * 64 + jq * 4]);
            P[widL][u][r][jq] = s.x * q4.x + s.y * q4.y + s.z * q4.z + s.w * q4.w;
        }
        const float* pr = &P[widL][ur2][rr][half * 8];
        f32x4 a0 = *(const f32x4*)pr;
        f32x4 a1 = *(const f32x4*)(pr + 4);
        float acc = (a0.x + a0.y) + (a0.z + a0.w) + (a1.x + a1.y) + (a1.z + a1.w);
        acc += __shfl_xor(acc, 1, 64);
        if (half == 0) {
            int t = t0 + tb + ur2;
            float sg = 1.0f / (1.0f + __expf(-acc));
            out[((size_t)t * B_DIM + b) * 64 + i0 + rr] = acc * acc * sg;
        }
    }
}

extern "C" void kernel_launch(void* const* d_in, const int* in_sizes, int n_in,
                              void* d_out, int out_size, void* d_ws, size_t ws_size,
                              hipStream_t stream) {
    const float* x  = (const float*)d_in[0];
    const float* S0 = (const float*)d_in[1];
    const float* Wk = (const float*)d_in[2];
    const float* Wv = (const float*)d_in[3];
    const float* Wq = (const float*)d_in[4];
    const float* uk = (const float*)d_in[5];
    const float* uv = (const float*)d_in[6];

    float* out   = (float*)d_out;                              // [T,B,n]
    float* S_all = out + (size_t)T_DIM * B_DIM * N_DIM;        // [T+1,B,n,n]

    float* ws    = (float*)d_ws;
    float* kvq   = ws;                                   // 16384*192
    unsigned short* BPh = (unsigned short*)(kvq + (size_t)16384 * 192);  // 192*1024
    unsigned short* BPl = BPh + (size_t)192 * D_DIM;
    float* G      = (float*)(BPl + (size_t)192 * D_DIM); // 2*64*64 floats

    gram_pack_kernel<<<192, 256, 0, stream>>>(Wk, Wv, Wq, G, BPh, BPl);
    proj_mfma_kernel<<<T_DIM * B_DIM / PBM, 256, 0, stream>>>(x, BPh, BPl, kvq);
    scan_kernel<<<NCHUNK * B_DIM * 4, 256, 0, stream>>>(kvq, S0, G, uk, uv, out, S_all);
}

// Round 23
// 112.025 us; speedup vs baseline: 1.0343x; 1.0343x over previous
//
#include <hip/hip_runtime.h>
#include <math.h>

#define T_DIM 2048
#define B_DIM 8
#define D_DIM 1024
#define N_DIM 64
#define NCHUNK 16
#define CHUNK_LEN 128              // T_DIM / NCHUNK
#define DECAY 0.9f
#define EPS 1e-8f
#define RADIUS 0.5f

typedef __attribute__((ext_vector_type(8))) short short8;   // bf16x8 MFMA frag
typedef __attribute__((ext_vector_type(4))) float f32x4;

static __device__ __forceinline__ unsigned short f2bf(float f) {
    unsigned u = __float_as_uint(f);
    u += 0x7FFFu + ((u >> 16) & 1u);          // RNE
    return (unsigned short)(u >> 16);
}
static __device__ __forceinline__ float bf2f(unsigned short h) {
    return __uint_as_float(((unsigned)h) << 16);
}

// counted barrier: flush LDS writes, sync waves, do NOT drain vmcnt (T4)
static __device__ __forceinline__ void bar_lgkm() {
    asm volatile("s_waitcnt lgkmcnt(0)" ::: "memory");
    __builtin_amdgcn_s_barrier();
    asm volatile("" ::: "memory");
}

// ---------------- Gram matrix: G[mat] = W W^T (64x64), 128 blocks ----------------
__global__ __launch_bounds__(256)
void gram_kernel(const float* __restrict__ Wk, const float* __restrict__ Wv,
                 float* __restrict__ G) {
    int mat = blockIdx.x >> 6;
    int i   = blockIdx.x & 63;
    const float* W = mat ? Wv : Wk;
    __shared__ float wsr[D_DIM];
    __shared__ float part[4][64];
    int tid = threadIdx.x;
    *(float4*)&wsr[tid * 4] = *(const float4*)(W + (size_t)i * D_DIM + tid * 4);
    __syncthreads();
    int j = tid & 63, p = tid >> 6;
    const float* wj = W + (size_t)j * D_DIM + p * 256;
    const float* wp = wsr + p * 256;
    float acc = 0.f;
    #pragma unroll 16
    for (int k = 0; k < 256; k += 4) {
        float4 a = *(const float4*)(wj + k);
        float4 b = *(const float4*)(wp + k);
        acc += a.x * b.x + a.y * b.y + a.z * b.z + a.w * b.w;
    }
    part[p][j] = acc;
    __syncthreads();
    if (tid < 64)
        G[((size_t)mat * 64 + i) * 64 + tid] =
            part[0][tid] + part[1][tid] + part[2][tid] + part[3][tid];
}

// ------- build (FUSED power iteration) + pack bf16 hi/lo, PACK-LINEAR -------
__global__ __launch_bounds__(256)
void build_wt_kernel(const float* __restrict__ Wk, const float* __restrict__ Wv,
                     const float* __restrict__ Wq, const float* __restrict__ G,
                     const float* __restrict__ uk, const float* __restrict__ uv,
                     unsigned short* __restrict__ BPh, unsigned short* __restrict__ BPl) {
    __shared__ float Gs[64][65];
    __shared__ float us_s[64];
    __shared__ float sc_s;
    int bid = blockIdx.x;          // 96 blocks
    int g   = bid >> 3;            // 0..11
    int gm  = g >> 2;              // matrix: 0=k,1=v,2=q
    int tid = threadIdx.x;

    if (gm < 2) {
        #pragma unroll
        for (int e = 0; e < 16; ++e) {
            int idx = e * 256 + tid;
            Gs[idx >> 6][idx & 63] = G[(size_t)gm * 4096 + idx];
        }
        if (tid < 64) us_s[tid] = (gm ? uv : uk)[tid];
        __syncthreads();               // Gs/us visible to wave 0
        if (tid < 64) {                // entire power iteration inside wave 0
            int i = tid;
            float sigma = 0.f;
            for (int it = 0; it < 3; ++it) {
                float t = 0.f;
                #pragma unroll
                for (int jj = 0; jj < 64; ++jj)
                    t += Gs[i][jj] * us_s[jj];
                float nv2 = us_s[i] * t;
                #pragma unroll
                for (int o = 32; o > 0; o >>= 1) nv2 += __shfl_xor(nv2, o, 64);
                float nv = sqrtf(fmaxf(nv2, 0.f));
                float ur = t / (nv + EPS);
                float nu2 = ur * ur;
                #pragma unroll
                for (int o = 32; o > 0; o >>= 1) nu2 += __shfl_xor(nu2, o, 64);
                float nu = sqrtf(nu2);
                if (it == 2) sigma = nu2 / (nu + EPS);
                us_s[i] = ur / (nu + EPS);   // wave-0-local LDS: no barrier needed
            }
            if (tid == 0) sc_s = RADIUS / (sigma + EPS);
        }
    } else {
        if (tid == 0) sc_s = 1.0f;
    }
    __syncthreads();
    float sc = sc_s;

    const float* W = (gm == 0) ? Wk : (gm == 1) ? Wv : Wq;
    int subb = bid & 7;
    int m    = subb * 256 + tid;       // chunk id 0..2047
    int s    = m >> 7;
    int kk   = (m >> 6) & 1;
    int flh  = (m >> 4) & 3;
    int fl   = m & 15;
    int row  = (g & 3) * 16 + fl;
    int k0   = s * 64 + kk * 32 + flh * 8;
    const float* src = W + (size_t)row * D_DIM + k0;
    float4 a = *(const float4*)src;
    float4 b = *(const float4*)(src + 4);
    float v[8] = {a.x, a.y, a.z, a.w, b.x, b.y, b.z, b.w};
    short8 hv, lv;
    #pragma unroll
    for (int e = 0; e < 8; ++e) {
        float val = v[e] * sc;
        unsigned short hh = f2bf(val);
        hv[e] = (short)hh;
        lv[e] = (short)f2bf(val - bf2f(hh));
    }
    size_t o = (size_t)g * 16384 + (size_t)m * 8;
    *(short8*)(BPh + o) = hv;
    *(short8*)(BPl + o) = lv;
}

// ------------- projections (R13 structure: PBM=32, 4 waves, 512 blocks) -------------
#define PBM 32
#define KSTAGE 128
__global__ __launch_bounds__(256)
void proj_mfma_kernel(const float* __restrict__ x,
                      const unsigned short* __restrict__ BPh,
                      const unsigned short* __restrict__ BPl,
                      float* __restrict__ kvq) {
    __shared__ __align__(16) unsigned short ldsA[2][PBM * KSTAGE];  // 16 KB
    int tid = threadIdx.x;
    int lane = tid & 63;
    int wv = tid >> 6;                 // 0..3 -> cols [wv*48, +48)
    int fl15 = lane & 15;
    int flh = lane >> 4;               // 0..3
    int rowBase = blockIdx.x * PBM;

    int r_st = tid >> 3;
    int sub  = tid & 7;
    const float* xrow = x + (size_t)(rowBase + r_st) * D_DIM + sub * 8;
    int wb0 = r_st * 256 + ((sub * 16) ^ ((r_st & 7) << 4));
    int wb1 = wb0 + 128;

    const unsigned short* bbh = BPh + (size_t)(wv * 3) * 16384 + lane * 8;
    const unsigned short* bbl = BPl + (size_t)(wv * 3) * 16384 + lane * 8;

    f32x4 acc[2][3];
    #pragma unroll
    for (int mt = 0; mt < 2; ++mt)
        #pragma unroll
        for (int nt = 0; nt < 3; ++nt) acc[mt][nt] = (f32x4)(0.f);

    // prologue: stage 0 -> buf0 (single bf16 plane); stage 1 -> regs p*
    {
        float4 c0 = *(const float4*)(xrow);
        float4 c1 = *(const float4*)(xrow + 4);
        float4 c2 = *(const float4*)(xrow + 64);
        float4 c3 = *(const float4*)(xrow + 68);
        float v0[8] = {c0.x, c0.y, c0.z, c0.w, c1.x, c1.y, c1.z, c1.w};
        float v1[8] = {c2.x, c2.y, c2.z, c2.w, c3.x, c3.y, c3.z, c3.w};
        short8 h0, h1;
        #pragma unroll
        for (int e = 0; e < 8; ++e) {
            h0[e] = (short)f2bf(v0[e]);
            h1[e] = (short)f2bf(v1[e]);
        }
        char* pH = (char*)&ldsA[0][0];
        *(short8*)(pH + wb0) = h0;
        *(short8*)(pH + wb1) = h1;
    }
    float4 p0 = *(const float4*)(xrow + KSTAGE);
    float4 p1 = *(const float4*)(xrow + KSTAGE + 4);
    float4 p2 = *(const float4*)(xrow + KSTAGE + 64);
    float4 p3 = *(const float4*)(xrow + KSTAGE + 68);
    bar_lgkm();

    #pragma unroll 1
    for (int qt = 0; qt < 8; ++qt) {
        int buf = qt & 1;
        const char* pH = (const char*)&ldsA[buf][0];
        #pragma unroll
        for (int s = 0; s < 2; ++s) {
            int sg = qt * 2 + s;
            short8 bh[2][3], bl[2][3];
            #pragma unroll
            for (int nt = 0; nt < 3; ++nt)
                #pragma unroll
                for (int kk = 0; kk < 2; ++kk) {
                    size_t off = (size_t)nt * 16384 + sg * 1024 + kk * 512;
                    bh[kk][nt] = *(const short8*)(bbh + off);
                    bl[kk][nt] = *(const short8*)(bbl + off);
                }
            #pragma unroll
            for (int kk = 0; kk < 2; ++kk) {
                short8 ah[2];
                #pragma unroll
                for (int mt = 0; mt < 2; ++mt) {
                    int row = mt * 16 + fl15;
                    int off = row * 256 + s * 128 +
                              ((kk * 64 + flh * 16) ^ ((row & 7) << 4));
                    ah[mt] = *(const short8*)(pH + off);
                }
                #pragma unroll
                for (int mt = 0; mt < 2; ++mt)
                    #pragma unroll
                    for (int nt = 0; nt < 3; ++nt) {
                        acc[mt][nt] = __builtin_amdgcn_mfma_f32_16x16x32_bf16(
                            ah[mt], bh[kk][nt], acc[mt][nt], 0, 0, 0);
                        acc[mt][nt] = __builtin_amdgcn_mfma_f32_16x16x32_bf16(
                            ah[mt], bl[kk][nt], acc[mt][nt], 0, 0, 0);
                    }
            }
        }
        // x prefetch for stage qt+2, issued after all B loads of this iter
        float4 q0, q1, q2, q3;
        if (qt < 6) {
            const float* nx = xrow + (qt + 2) * KSTAGE;
            q0 = *(const float4*)(nx);
            q1 = *(const float4*)(nx + 4);
            q2 = *(const float4*)(nx + 64);
            q3 = *(const float4*)(nx + 68);
        }
        // write stage qt+1 (regs p*) into the other buffer
        if (qt < 7) {
            float v0[8] = {p0.x, p0.y, p0.z, p0.w, p1.x, p1.y, p1.z, p1.w};
            float v1[8] = {p2.x, p2.y, p2.z, p2.w, p3.x, p3.y, p3.z, p3.w};
            short8 h0, h1;
            #pragma unroll
            for (int e = 0; e < 8; ++e) {
                h0[e] = (short)f2bf(v0[e]);
                h1[e] = (short)f2bf(v1[e]);
            }
            char* qH = (char*)&ldsA[buf ^ 1][0];
            *(short8*)(qH + wb0) = h0;
            *(short8*)(qH + wb1) = h1;
        }
        bar_lgkm();
        p0 = q0; p1 = q1; p2 = q2; p3 = q3;
    }

    // epilogue: C/D layout col=lane&15, row=(lane>>4)*4+reg  [m89]
    #pragma unroll
    for (int mt = 0; mt < 2; ++mt)
        #pragma unroll
        for (int nt = 0; nt < 3; ++nt) {
            int col = wv * 48 + nt * 16 + fl15;
            #pragma unroll
            for (int r = 0; r < 4; ++r) {
                int row = rowBase + mt * 16 + flh * 4 + r;
                kvq[(size_t)row * 192 + col] = acc[mt][nt][r];
            }
        }
}

// ------------- scan with fused in-register warm-up carry -------------
#define SC_TILE 8
__global__ __launch_bounds__(256)
void scan_kernel(const float* __restrict__ kvq,
                 const float* __restrict__ S0,
                 float* __restrict__ out,      // [T,B,n]
                 float* __restrict__ S_all) {  // [T+1,B,n,n]
    __shared__ __align__(16) float P[4][SC_TILE][4][20];
    int widL = threadIdx.x >> 6;
    int lane = threadIdx.x & 63;
    int r  = lane >> 4;          // row within wave's 4
    int jq = lane & 15;          // col quad
    int blk = blockIdx.x;
    int c  = blk >> 5;           // 0..15
    int b  = (blk >> 2) & 7;
    int ig = blk & 3;
    int i0 = ig * 16 + widL * 4;
    int i  = i0 + r;

    int pp   = lane >> 1;
    int ur   = pp >> 2;
    int rr   = pp & 3;
    int half = lane & 1;

    if (c == 0) {
        f32x4 s0v = *(const f32x4*)&S0[((size_t)b * 64 + i) * 64 + jq * 4];
        *(f32x4*)&S_all[(size_t)b * 4096 + (size_t)i * 64 + jq * 4] = s0v;
    }

    f32x4 s = (f32x4)(0.f);
    if (c > 0) {
        int tp = (c - 1) * CHUNK_LEN;
        #pragma unroll 4
        for (int u = 0; u < CHUNK_LEN; ++u) {
            const float* base = kvq + (size_t)((tp + u) * B_DIM + b) * 192;
            f32x4 k4 = *(const f32x4*)(base + jq * 4);
            float v  = base[64 + i];
            s.x = __builtin_fmaf(DECAY, s.x, v * k4.x);
            s.y = __builtin_fmaf(DECAY, s.y, v * k4.y);
            s.z = __builtin_fmaf(DECAY, s.z, v * k4.z);
            s.w = __builtin_fmaf(DECAY, s.w, v * k4.w);
        }
    }

    int t0 = c * CHUNK_LEN;
    for (int tb = 0; tb < CHUNK_LEN; tb += SC_TILE) {
        #pragma unroll
        for (int u = 0; u < SC_TILE; ++u) {
            int t = t0 + tb + u;
            const float* base = kvq + (size_t)(t * B_DIM + b) * 192;
            f32x4 k4 = *(const f32x4*)(base + jq * 4);
            f32x4 q4 = *(const f32x4*)(base + 128 + jq * 4);
            float v  = base[64 + i];
            s.x = __builtin_fmaf(DECAY, s.x, v * k4.x);
            s.y = __builtin_fmaf(DECAY, s.y, v * k4.y);
            s.z = __builtin_fmaf(DECAY, s.z, v * k4.z);
            s.w = __builtin_fmaf(DECAY, s.w, v * k4.w);
            __builtin_nontemporal_store(
                s, (f32x4*)&S_all[((size_t)(t + 1) * B_DIM + b) * 4096 +
                                  (size_t)i * 64 + jq * 4]);
            P[widL][u][r][jq] = s.x * q4.x + s.y * q4.y + s.z * q4.z + s.w * q4.w;
        }
        const float* pr = &P[widL][ur][rr][half * 8];
        f32x4 a0 = *(const f32x4*)pr;
        f32x4 a1 = *(const f32x4*)(pr + 4);
        float acc = (a0.x + a0.y) + (a0.z + a0.w) + (a1.x + a1.y) + (a1.z + a1.w);
        acc += __shfl_xor(acc, 1, 64);
        if (half == 0) {
            int t = t0 + tb + ur;
            float sg = 1.0f / (1.0f + __expf(-acc));
            out[((size_t)t * B_DIM + b) * 64 + i0 + rr] = acc * acc * sg;
        }
    }
}

extern "C" void kernel_launch(void* const* d_in, const int* in_sizes, int n_in,
                              void* d_out, int out_size, void* d_ws, size_t ws_size,
                              hipStream_t stream) {
    const float* x  = (const float*)d_in[0];
    const float* S0 = (const float*)d_in[1];
    const float* Wk = (const float*)d_in[2];
    const float* Wv = (const float*)d_in[3];
    const float* Wq = (const float*)d_in[4];
    const float* uk = (const float*)d_in[5];
    const float* uv = (const float*)d_in[6];

    float* out   = (float*)d_out;                              // [T,B,n]
    float* S_all = out + (size_t)T_DIM * B_DIM * N_DIM;        // [T+1,B,n,n]

    float* ws    = (float*)d_ws;
    float* kvq   = ws;                                   // 16384*192
    unsigned short* BPh = (unsigned short*)(kvq + (size_t)16384 * 192);  // 192*1024
    unsigned short* BPl = BPh + (size_t)192 * D_DIM;
    float* G      = (float*)(BPl + (size_t)192 * D_DIM); // 2*64*64 floats

    gram_kernel<<<128, 256, 0, stream>>>(Wk, Wv, G);
    build_wt_kernel<<<96, 256, 0, stream>>>(Wk, Wv, Wq, G, uk, uv, BPh, BPl);
    proj_mfma_kernel<<<T_DIM * B_DIM / PBM, 256, 0, stream>>>(x, BPh, BPl, kvq);
    scan_kernel<<<NCHUNK * B_DIM * 4, 256, 0, stream>>>(kvq, S0, out, S_all);
}